// Round 1
// baseline (8205.887 us; speedup 1.0000x reference)
//
#include <hip/hip_runtime.h>
#include <hip/hip_bf16.h>

// Fishnet: per-point net (64->152) -> L (16x16 lower) -> F = L L^T,
// segment-sum F,t -> solve (F+I)x=1 -> theta = x*t_red -> theta @ proj_W.
// Round 1: fp32 baseline. Stage A: point kernel with LDS-staged data tile,
// register-resident L[136], atomic scatter-add. Stage B: per-segment packed
// Cholesky solve + GEMV.

#define N_PTS   1000000
#define DIM     64
#define INNER   16
#define OUTD    64
#define NSEG    100000
#define NTRI    136          // 16*17/2
#define NET_OUT 152          // NTRI + INNER

__device__ __host__ __forceinline__ constexpr int tri(int i) { return i * (i + 1) / 2; }

__device__ __forceinline__ float fast_tanh(float x) {
    float e = __expf(2.0f * x);
    return 1.0f - __fdividef(2.0f, e + 1.0f);   // exact at +/-inf
}
__device__ __forceinline__ float fast_softplus(float x) {
    // arg range here: x = tanh(y) in (-1,1) -> no overflow concerns
    return __logf(1.0f + __expf(x));
}

// ---------------------------------------------------------------------------
// Stage A: one thread per point. Block stages 256 points (256x64 fp32) into
// 64KB LDS (XOR-swizzled at float4 granularity: 2..4-way conflicts, hidden
// behind 8 FMA per ds_read_b128). net_out computed in 8-wide column chunks
// (W reads are wave-uniform -> scalar loads). L kept in registers (all
// indices compile-time via full unroll of the chunk loop).
// ---------------------------------------------------------------------------
__global__ __launch_bounds__(256, 2)
void points_kernel(const float* __restrict__ data,
                   const int*   __restrict__ segs,
                   const float* __restrict__ W,
                   const float* __restrict__ bias,
                   float* __restrict__ Fred,
                   float* __restrict__ tred)
{
    __shared__ float4 tile[256 * 16];   // 65536 B
    const int t    = threadIdx.x;
    const int base = blockIdx.x * 256;
    const int nvalid = min(256, N_PTS - base);

    const float4* g = (const float4*)data + (size_t)base * 16;
    #pragma unroll
    for (int i = 0; i < 16; ++i) {
        int idx = t + i * 256;              // 0..4095 float4s of this block
        int pl  = idx >> 4;                 // point-local
        int c4  = idx & 15;                 // float4 column
        if (pl < nvalid)
            tile[pl * 16 + (c4 ^ (pl & 15))] = g[idx];
    }
    __syncthreads();

    const int p = base + t;
    if (p >= N_PTS) return;
    const int seg = segs[p];

    const int rbase = t * 16;
    const int rsw   = t & 15;

    // ---- t = net_out[:, :16] -> immediate atomic accumulation ----
    #pragma unroll
    for (int jc = 0; jc < INNER; jc += 8) {
        float acc[8];
        #pragma unroll
        for (int u = 0; u < 8; ++u) acc[u] = bias[jc + u];
        #pragma unroll 2
        for (int k4 = 0; k4 < 16; ++k4) {
            float4 r = tile[rbase + (k4 ^ rsw)];
            float rv0 = r.x, rv1 = r.y, rv2 = r.z, rv3 = r.w;
            const float* w0 = &W[(k4 * 4 + 0) * NET_OUT + jc];
            const float* w1 = &W[(k4 * 4 + 1) * NET_OUT + jc];
            const float* w2 = &W[(k4 * 4 + 2) * NET_OUT + jc];
            const float* w3 = &W[(k4 * 4 + 3) * NET_OUT + jc];
            #pragma unroll
            for (int u = 0; u < 8; ++u) {
                acc[u] = fmaf(rv0, w0[u], acc[u]);
                acc[u] = fmaf(rv1, w1[u], acc[u]);
                acc[u] = fmaf(rv2, w2[u], acc[u]);
                acc[u] = fmaf(rv3, w3[u], acc[u]);
            }
        }
        #pragma unroll
        for (int u = 0; u < 8; ++u)
            atomicAdd(&tred[(size_t)seg * INNER + jc + u], acc[u]);
    }

    // ---- y = net_out[:, 16:] -> L (packed lower-tri, registers) ----
    float L[NTRI];
    #pragma unroll
    for (int jc = INNER; jc < NET_OUT; jc += 8) {
        float acc[8];
        #pragma unroll
        for (int u = 0; u < 8; ++u) acc[u] = bias[jc + u];
        #pragma unroll 2
        for (int k4 = 0; k4 < 16; ++k4) {
            float4 r = tile[rbase + (k4 ^ rsw)];
            float rv0 = r.x, rv1 = r.y, rv2 = r.z, rv3 = r.w;
            const float* w0 = &W[(k4 * 4 + 0) * NET_OUT + jc];
            const float* w1 = &W[(k4 * 4 + 1) * NET_OUT + jc];
            const float* w2 = &W[(k4 * 4 + 2) * NET_OUT + jc];
            const float* w3 = &W[(k4 * 4 + 3) * NET_OUT + jc];
            #pragma unroll
            for (int u = 0; u < 8; ++u) {
                acc[u] = fmaf(rv0, w0[u], acc[u]);
                acc[u] = fmaf(rv1, w1[u], acc[u]);
                acc[u] = fmaf(rv2, w2[u], acc[u]);
                acc[u] = fmaf(rv3, w3[u], acc[u]);
            }
        }
        #pragma unroll
        for (int u = 0; u < 8; ++u)
            L[jc - INNER + u] = fast_tanh(acc[u]);
    }
    // diagonal: softplus applied ON TOP of tanh (matches reference order)
    #pragma unroll
    for (int i = 0; i < INNER; ++i)
        L[tri(i) + i] = fast_softplus(L[tri(i) + i]);

    // ---- F = L L^T (lower triangle only) -> atomic scatter-add ----
    float* frow = &Fred[(size_t)seg * NTRI];
    #pragma unroll
    for (int i = 0; i < INNER; ++i) {
        #pragma unroll
        for (int j = 0; j <= i; ++j) {
            float s = 0.0f;
            #pragma unroll
            for (int k = 0; k <= j; ++k)
                s = fmaf(L[tri(i) + k], L[tri(j) + k], s);
            atomicAdd(&frow[tri(i) + j], s);
        }
    }
}

// ---------------------------------------------------------------------------
// Stage B: one thread per segment. A = F_red + I (SPD, diag >= 1).
// Packed-lower Cholesky, solve A x = 1 (colsum of A^-1 by symmetry),
// theta = x .* t_red, out = theta @ proj_W.
// ---------------------------------------------------------------------------
__global__ __launch_bounds__(256, 2)
void seg_kernel(const float* __restrict__ Fred,
                const float* __restrict__ tred,
                const float* __restrict__ projW,
                float* __restrict__ out)
{
    const int s = blockIdx.x * 256 + threadIdx.x;
    if (s >= NSEG) return;

    float a[NTRI];
    const float4* f4 = (const float4*)(Fred + (size_t)s * NTRI);
    #pragma unroll
    for (int q = 0; q < NTRI / 4; ++q) {
        float4 v = f4[q];
        a[4 * q + 0] = v.x; a[4 * q + 1] = v.y;
        a[4 * q + 2] = v.z; a[4 * q + 3] = v.w;
    }
    #pragma unroll
    for (int i = 0; i < INNER; ++i) a[tri(i) + i] += 1.0f;

    // in-place packed Cholesky
    #pragma unroll
    for (int j = 0; j < INNER; ++j) {
        float d = a[tri(j) + j];
        #pragma unroll
        for (int k = 0; k < j; ++k)
            d = fmaf(-a[tri(j) + k], a[tri(j) + k], d);
        d = sqrtf(d);
        a[tri(j) + j] = d;
        float dinv = __fdividef(1.0f, d);
        #pragma unroll
        for (int i = j + 1; i < INNER; ++i) {
            float v = a[tri(i) + j];
            #pragma unroll
            for (int k = 0; k < j; ++k)
                v = fmaf(-a[tri(i) + k], a[tri(j) + k], v);
            a[tri(i) + j] = v * dinv;
        }
    }
    // forward solve  L z = 1
    float z[INNER];
    #pragma unroll
    for (int i = 0; i < INNER; ++i) {
        float v = 1.0f;
        #pragma unroll
        for (int k = 0; k < i; ++k)
            v = fmaf(-a[tri(i) + k], z[k], v);
        z[i] = __fdividef(v, a[tri(i) + i]);
    }
    // back solve  L^T x = z
    float x[INNER];
    #pragma unroll
    for (int i = INNER - 1; i >= 0; --i) {
        float v = z[i];
        #pragma unroll
        for (int k = i + 1; k < INNER; ++k)
            v = fmaf(-a[tri(k) + i], x[k], v);
        x[i] = __fdividef(v, a[tri(i) + i]);
    }
    // theta = x .* t_red
    float theta[INNER];
    const float4* t4 = (const float4*)(tred + (size_t)s * INNER);
    #pragma unroll
    for (int q = 0; q < 4; ++q) {
        float4 v = t4[q];
        theta[4 * q + 0] = v.x * x[4 * q + 0];
        theta[4 * q + 1] = v.y * x[4 * q + 1];
        theta[4 * q + 2] = v.z * x[4 * q + 2];
        theta[4 * q + 3] = v.w * x[4 * q + 3];
    }
    // out[s, :] = theta @ proj_W   (proj_W reads are wave-uniform)
    float* orow = out + (size_t)s * OUTD;
    for (int oc = 0; oc < OUTD; oc += 8) {
        float acc[8] = {0, 0, 0, 0, 0, 0, 0, 0};
        #pragma unroll
        for (int j = 0; j < INNER; ++j) {
            float th = theta[j];
            #pragma unroll
            for (int u = 0; u < 8; ++u)
                acc[u] = fmaf(th, projW[j * OUTD + oc + u], acc[u]);
        }
        float4 v0 = {acc[0], acc[1], acc[2], acc[3]};
        float4 v1 = {acc[4], acc[5], acc[6], acc[7]};
        ((float4*)(orow + oc))[0] = v0;
        ((float4*)(orow + oc))[1] = v1;
    }
}

extern "C" void kernel_launch(void* const* d_in, const int* in_sizes, int n_in,
                              void* d_out, int out_size, void* d_ws, size_t ws_size,
                              hipStream_t stream)
{
    const float* data  = (const float*)d_in[0];
    const int*   segs  = (const int*)d_in[1];
    // d_in[2] = num_segments scalar (compile-time NSEG)
    const float* W     = (const float*)d_in[3];
    const float* bias  = (const float*)d_in[4];
    const float* projW = (const float*)d_in[5];

    float* Fred = (float*)d_ws;                       // NSEG * 136
    float* tred = Fred + (size_t)NSEG * NTRI;         // NSEG * 16

    hipMemsetAsync(d_ws, 0, (size_t)NSEG * (NTRI + INNER) * sizeof(float), stream);

    points_kernel<<<(N_PTS + 255) / 256, 256, 0, stream>>>(data, segs, W, bias, Fred, tred);
    seg_kernel<<<(NSEG + 255) / 256, 256, 0, stream>>>(Fred, tred, projW, (float*)d_out);
}

// Round 2
// 1398.079 us; speedup vs baseline: 5.8694x; 5.8694x over previous
//
#include <hip/hip_runtime.h>
#include <hip/hip_bf16.h>

// Fishnet round 2: counting-sort by segment, then wave-per-segment gather.
// Kills the 152M fp32 atomics (4.86 GB HBM RMW traffic) that made round 1
// atomic-bound at 7.9 ms / VALUBusy 3%.
//
// Pipeline:
//   K1 hist:    rank[p] = atomicAdd(cnt[seg[p]], 1)          (1M int atomics)
//   K2 scan:    off = exclusive_scan(cnt)                    (3 tiny kernels)
//   K3 scatter: sorted[off[seg]+rank[p]] = p                 (plain stores)
//   K4 main:    wave-per-segment: for each point, scalar-load data row
//               (wave-uniform p -> s_load into SGPRs), 192 register-cached W
//               columns per lane -> net_out; tanh/softplus -> L staged in a
//               zero-padded stride-20 LDS tile; lane (q,i) accumulates
//               F(i, q+4u) via ds_read_b128 row dots. Writes Fred/tred once.
//   K5 seg:     per-thread packed Cholesky solve + GEMV (unchanged, verified)

#define N_PTS   1000000
#define DIM     64
#define INNER   16
#define OUTD    64
#define NSEG    100000
#define NTRI    136          // 16*17/2
#define NET_OUT 152          // NTRI + INNER
#define NB      391          // ceil(NSEG/256)

__device__ __host__ __forceinline__ constexpr int tri(int i) { return i * (i + 1) / 2; }

__device__ __forceinline__ float fast_tanh(float x) {
    float e = __expf(2.0f * x);
    return 1.0f - __fdividef(2.0f, e + 1.0f);
}
__device__ __forceinline__ float fast_softplus(float x) {
    return __logf(1.0f + __expf(x));
}

// In-wave LDS producer->consumer ordering: DS pipe is in-order per wave;
// wave_barrier blocks compiler reordering, s_waitcnt lgkmcnt(0) drains DS.
// imm 0xC07F = vmcnt=63, expcnt=7, lgkmcnt=0 (gfx9 encoding).
__device__ __forceinline__ void wave_lds_sync() {
    __builtin_amdgcn_wave_barrier();
    __builtin_amdgcn_s_waitcnt(0xC07F);
    __builtin_amdgcn_wave_barrier();
}

// packed-tri index -> (row, col, is_diag); unrolled so tri(k) is constant
__device__ __forceinline__ void ecoord(int e, int& r, int& c, bool& dg) {
    int rr = 0;
    #pragma unroll
    for (int k = 1; k < 16; ++k) rr = (e >= tri(k)) ? k : rr;
    r = rr; c = e - tri(rr); dg = (c == rr);
}

// ---------------------------------------------------------------------------
__global__ __launch_bounds__(256) void hist_kernel(const int* __restrict__ segs,
                                                   int* __restrict__ cnt,
                                                   int* __restrict__ rank)
{
    int t = blockIdx.x * 256 + threadIdx.x;
    if (t < N_PTS) rank[t] = atomicAdd(&cnt[segs[t]], 1);
}

__global__ __launch_bounds__(256) void scan_blocks(const int* __restrict__ cnt,
                                                   int* __restrict__ off,
                                                   int* __restrict__ bsum)
{
    __shared__ int sh[256];
    const int t = threadIdx.x;
    const int i = blockIdx.x * 256 + t;
    int v = (i < NSEG) ? cnt[i] : 0;
    sh[t] = v;
    __syncthreads();
    #pragma unroll
    for (int d = 1; d < 256; d <<= 1) {
        int add = (t >= d) ? sh[t - d] : 0;
        __syncthreads();
        sh[t] += add;
        __syncthreads();
    }
    if (i < NSEG) off[i] = sh[t] - v;            // exclusive within block
    if (t == 255) bsum[blockIdx.x] = sh[t];      // block total
}

__global__ __launch_bounds__(512) void scan_top(int* __restrict__ bsum)
{
    __shared__ int sh[512];
    const int t = threadIdx.x;
    int v = (t < NB) ? bsum[t] : 0;
    sh[t] = v;
    __syncthreads();
    #pragma unroll
    for (int d = 1; d < 512; d <<= 1) {
        int add = (t >= d) ? sh[t - d] : 0;
        __syncthreads();
        sh[t] += add;
        __syncthreads();
    }
    if (t < NB) bsum[t] = sh[t] - v;             // exclusive
}

__global__ __launch_bounds__(256) void scan_add(int* __restrict__ off,
                                                const int* __restrict__ bsum)
{
    int i = blockIdx.x * 256 + threadIdx.x;
    if (i < NSEG) off[i] += bsum[blockIdx.x];
}

__global__ __launch_bounds__(256) void scatter_kernel(const int* __restrict__ segs,
                                                      const int* __restrict__ off,
                                                      const int* __restrict__ rank,
                                                      int* __restrict__ sorted)
{
    int t = blockIdx.x * 256 + threadIdx.x;
    if (t < N_PTS) sorted[off[segs[t]] + rank[t]] = t;
}

// ---------------------------------------------------------------------------
// K4: one wave per segment (grid-stride). Lane l owns net-out columns
// {l, l+64, l+128(l<24)}; F-phase lane (q=l>>4, i=l&15) owns F(i, q+4u).
// ---------------------------------------------------------------------------
__global__ __launch_bounds__(256, 2)
void main_kernel(const float* __restrict__ data,
                 const int*   __restrict__ sorted,
                 const int*   __restrict__ off,
                 const int*   __restrict__ cnt,
                 const float* __restrict__ W,
                 const float* __restrict__ bias,
                 float* __restrict__ Fred,
                 float* __restrict__ tred)
{
    __shared__ float lds[4 * 320];               // 4 waves x (16 rows, stride 20)
    const int l = threadIdx.x & 63;
    const int w = threadIdx.x >> 6;
    float* Lm = &lds[w * 320];

    // zero the tile once; strict-upper positions are never written again,
    // so full-16 row dots are exact (pad contributes 0)
    #pragma unroll
    for (int u = 0; u < 5; ++u) Lm[u * 64 + l] = 0.0f;
    wave_lds_sync();

    const int q = l >> 4;
    const int i = l & 15;

    // per-lane packed-output coordinates
    int r0, c0, r1, c1, r2, c2; bool d0, d1, d2;
    { int e0 = l - 16; if (e0 < 0) e0 = 0; ecoord(e0, r0, c0, d0); }
    { int e1 = l + 48;                     ecoord(e1, r1, c1, d1); }
    { int e2 = (l < 24) ? (l + 112) : 0;   ecoord(e2, r2, c2, d2); }

    // register-cache 3 columns of W per lane (192 VGPRs) + bias
    float Wr0[64], Wr1[64], Wr2[64];
    #pragma unroll
    for (int k = 0; k < DIM; ++k) {
        Wr0[k] = W[k * NET_OUT + l];
        Wr1[k] = W[k * NET_OUT + 64 + l];
        Wr2[k] = (l < 24) ? W[k * NET_OUT + 128 + l] : 0.0f;
    }
    const float b0 = bias[l];
    const float b1 = bias[64 + l];
    const float b2 = (l < 24) ? bias[128 + l] : 0.0f;

    const int nwaves = gridDim.x * 4;
    for (int sid = blockIdx.x * 4 + w; sid < NSEG; sid += nwaves) {
        const int start = off[sid];
        const int n_s   = cnt[sid];
        float facc[4] = {0.0f, 0.0f, 0.0f, 0.0f};
        float tacc = 0.0f;

        for (int n = 0; n < n_s; ++n) {
            int p = __builtin_amdgcn_readfirstlane(sorted[start + n]);
            const float* xrow = data + (size_t)p * DIM;   // wave-uniform -> s_load

            float a0 = b0, a1 = b1, a2 = b2;
            #pragma unroll
            for (int k = 0; k < DIM; ++k) {
                float xk = xrow[k];
                a0 = fmaf(xk, Wr0[k], a0);
                a1 = fmaf(xk, Wr1[k], a1);
                a2 = fmaf(xk, Wr2[k], a2);
            }

            float t0 = fast_tanh(a0); if (d0) t0 = fast_softplus(t0);
            float t1 = fast_tanh(a1); if (d1) t1 = fast_softplus(t1);
            float t2 = fast_tanh(a2); if (d2) t2 = fast_softplus(t2);
            tacc += (l < 16) ? a0 : 0.0f;    // t = raw net_out[:, :16]

            wave_lds_sync();                 // WAR vs previous F-phase reads
            if (l >= 16) Lm[r0 * 20 + c0] = t0;
            Lm[r1 * 20 + c1] = t1;
            if (l < 24)  Lm[r2 * 20 + c2] = t2;
            wave_lds_sync();                 // RAW: writes visible to all lanes

            // F(i, q+4u) += row_i . row_j  (full 16; pad is zero)
            const float4 ri0 = *(const float4*)&Lm[i * 20 + 0];
            const float4 ri1 = *(const float4*)&Lm[i * 20 + 4];
            const float4 ri2 = *(const float4*)&Lm[i * 20 + 8];
            const float4 ri3 = *(const float4*)&Lm[i * 20 + 12];
            #pragma unroll
            for (int u = 0; u < 4; ++u) {
                const int j = q + 4 * u;
                const float4 rj0 = *(const float4*)&Lm[j * 20 + 0];
                const float4 rj1 = *(const float4*)&Lm[j * 20 + 4];
                const float4 rj2 = *(const float4*)&Lm[j * 20 + 8];
                const float4 rj3 = *(const float4*)&Lm[j * 20 + 12];
                float s = ri0.x * rj0.x;
                s = fmaf(ri0.y, rj0.y, s); s = fmaf(ri0.z, rj0.z, s); s = fmaf(ri0.w, rj0.w, s);
                s = fmaf(ri1.x, rj1.x, s); s = fmaf(ri1.y, rj1.y, s);
                s = fmaf(ri1.z, rj1.z, s); s = fmaf(ri1.w, rj1.w, s);
                s = fmaf(ri2.x, rj2.x, s); s = fmaf(ri2.y, rj2.y, s);
                s = fmaf(ri2.z, rj2.z, s); s = fmaf(ri2.w, rj2.w, s);
                s = fmaf(ri3.x, rj3.x, s); s = fmaf(ri3.y, rj3.y, s);
                s = fmaf(ri3.z, rj3.z, s); s = fmaf(ri3.w, rj3.w, s);
                facc[u] += s;
            }
        }

        #pragma unroll
        for (int u = 0; u < 4; ++u) {
            const int j = q + 4 * u;
            if (j <= i) Fred[(size_t)sid * NTRI + tri(i) + j] = facc[u];
        }
        if (l < 16) tred[(size_t)sid * INNER + l] = tacc;
    }
}

// ---------------------------------------------------------------------------
// K5: one thread per segment. A = F_red + I (SPD). Packed Cholesky,
// solve A x = 1 (colsum of A^-1 by symmetry), theta = x .* t_red,
// out = theta @ proj_W.  (unchanged from round 1 — verified)
// ---------------------------------------------------------------------------
__global__ __launch_bounds__(256, 2)
void seg_kernel(const float* __restrict__ Fred,
                const float* __restrict__ tred,
                const float* __restrict__ projW,
                float* __restrict__ out)
{
    const int s = blockIdx.x * 256 + threadIdx.x;
    if (s >= NSEG) return;

    float a[NTRI];
    const float4* f4 = (const float4*)(Fred + (size_t)s * NTRI);
    #pragma unroll
    for (int qq = 0; qq < NTRI / 4; ++qq) {
        float4 v = f4[qq];
        a[4 * qq + 0] = v.x; a[4 * qq + 1] = v.y;
        a[4 * qq + 2] = v.z; a[4 * qq + 3] = v.w;
    }
    #pragma unroll
    for (int ii = 0; ii < INNER; ++ii) a[tri(ii) + ii] += 1.0f;

    #pragma unroll
    for (int j = 0; j < INNER; ++j) {
        float d = a[tri(j) + j];
        #pragma unroll
        for (int k = 0; k < j; ++k)
            d = fmaf(-a[tri(j) + k], a[tri(j) + k], d);
        d = sqrtf(d);
        a[tri(j) + j] = d;
        float dinv = __fdividef(1.0f, d);
        #pragma unroll
        for (int ii = j + 1; ii < INNER; ++ii) {
            float v = a[tri(ii) + j];
            #pragma unroll
            for (int k = 0; k < j; ++k)
                v = fmaf(-a[tri(ii) + k], a[tri(j) + k], v);
            a[tri(ii) + j] = v * dinv;
        }
    }
    float z[INNER];
    #pragma unroll
    for (int ii = 0; ii < INNER; ++ii) {
        float v = 1.0f;
        #pragma unroll
        for (int k = 0; k < ii; ++k)
            v = fmaf(-a[tri(ii) + k], z[k], v);
        z[ii] = __fdividef(v, a[tri(ii) + ii]);
    }
    float x[INNER];
    #pragma unroll
    for (int ii = INNER - 1; ii >= 0; --ii) {
        float v = z[ii];
        #pragma unroll
        for (int k = ii + 1; k < INNER; ++k)
            v = fmaf(-a[tri(k) + ii], x[k], v);
        x[ii] = __fdividef(v, a[tri(ii) + ii]);
    }
    float theta[INNER];
    const float4* t4 = (const float4*)(tred + (size_t)s * INNER);
    #pragma unroll
    for (int qq = 0; qq < 4; ++qq) {
        float4 v = t4[qq];
        theta[4 * qq + 0] = v.x * x[4 * qq + 0];
        theta[4 * qq + 1] = v.y * x[4 * qq + 1];
        theta[4 * qq + 2] = v.z * x[4 * qq + 2];
        theta[4 * qq + 3] = v.w * x[4 * qq + 3];
    }
    float* orow = out + (size_t)s * OUTD;
    for (int oc = 0; oc < OUTD; oc += 8) {
        float acc[8] = {0, 0, 0, 0, 0, 0, 0, 0};
        #pragma unroll
        for (int j = 0; j < INNER; ++j) {
            float th = theta[j];
            #pragma unroll
            for (int u = 0; u < 8; ++u)
                acc[u] = fmaf(th, projW[j * OUTD + oc + u], acc[u]);
        }
        float4 v0 = {acc[0], acc[1], acc[2], acc[3]};
        float4 v1 = {acc[4], acc[5], acc[6], acc[7]};
        ((float4*)(orow + oc))[0] = v0;
        ((float4*)(orow + oc))[1] = v1;
    }
}

extern "C" void kernel_launch(void* const* d_in, const int* in_sizes, int n_in,
                              void* d_out, int out_size, void* d_ws, size_t ws_size,
                              hipStream_t stream)
{
    const float* data  = (const float*)d_in[0];
    const int*   segs  = (const int*)d_in[1];
    // d_in[2] = num_segments (compile-time NSEG)
    const float* W     = (const float*)d_in[3];
    const float* bias  = (const float*)d_in[4];
    const float* projW = (const float*)d_in[5];

    int* cnt     = (int*)d_ws;                        // NSEG
    int* off     = cnt + NSEG;                        // NSEG
    int* bsum    = off + NSEG;                        // 512
    int* rank    = bsum + 512;                        // N_PTS
    int* sorted  = rank + N_PTS;                      // N_PTS
    float* Fred  = (float*)(sorted + N_PTS);          // NSEG*NTRI (16B aligned)
    float* tred  = Fred + (size_t)NSEG * NTRI;        // NSEG*INNER
    // total ~69.6 MB

    hipMemsetAsync(cnt, 0, NSEG * sizeof(int), stream);

    hist_kernel   <<<(N_PTS + 255) / 256, 256, 0, stream>>>(segs, cnt, rank);
    scan_blocks   <<<NB, 256, 0, stream>>>(cnt, off, bsum);
    scan_top      <<<1, 512, 0, stream>>>(bsum);
    scan_add      <<<NB, 256, 0, stream>>>(off, bsum);
    scatter_kernel<<<(N_PTS + 255) / 256, 256, 0, stream>>>(segs, off, rank, sorted);
    main_kernel   <<<2048, 256, 0, stream>>>(data, sorted, off, cnt, W, bias, Fred, tred);
    seg_kernel    <<<NB, 256, 0, stream>>>(Fred, tred, projW, (float*)d_out);
}

// Round 3
// 720.518 us; speedup vs baseline: 11.3889x; 1.9404x over previous
//
#include <hip/hip_runtime.h>
#include <hip/hip_bf16.h>

// Fishnet round 3: full-MFMA fused main kernel.
//   - tiles of 16 consecutive SORTED points; net_out via mfma_f32_16x16x32_bf16
//     (M=16 points, N=152 in 10 col-tiles, K=64 in 2 steps; W register-cached)
//   - activations -> L image (bf16) in LDS (16 rows x stride-24 cols per point)
//   - F += L L^T per point via ONE K=32 MFMA (A==B fragment, k>=16 zero),
//     accumulating across points of a segment in the C-layout accumulator;
//     flush to Fred/tred at segment boundaries (wave owns whole segments)
//   - t via in-register prefix sum + shuffle at flush
// Aux: hist/scan/scatter counting sort (round 2, verified), seg Cholesky solve
// (round 1, verified; + empty-segment guard).

#define N_PTS   1000000
#define DIM     64
#define INNER   16
#define OUTD    64
#define NSEG    100000
#define NTRI    136
#define NET_OUT 152
#define NB      391          // ceil(NSEG/256)
#define SEGW    7            // segments per wave in main_kernel
#define NWAVES  ((NSEG + SEGW - 1) / SEGW)
#define MAINB   ((NWAVES + 3) / 4)

typedef short bf16x8 __attribute__((ext_vector_type(8)));
typedef float f32x4  __attribute__((ext_vector_type(4)));

__device__ __host__ __forceinline__ constexpr int tri(int i) { return i * (i + 1) / 2; }

__device__ __forceinline__ float fast_tanh(float x) {
    float e = __expf(2.0f * x);
    return 1.0f - __fdividef(2.0f, e + 1.0f);
}
__device__ __forceinline__ float fast_softplus(float x) {
    return __logf(1.0f + __expf(x));
}
__device__ __forceinline__ short f2bf(float f) {   // RNE fp32 -> bf16 bits
    unsigned u = __float_as_uint(f);
    return (short)((u + 0x7FFF + ((u >> 16) & 1)) >> 16);
}

// in-wave LDS producer->consumer ordering (validated round 2)
__device__ __forceinline__ void wave_lds_sync() {
    __builtin_amdgcn_wave_barrier();
    __builtin_amdgcn_s_waitcnt(0xC07F);   // lgkmcnt(0)
    __builtin_amdgcn_wave_barrier();
}

__device__ __forceinline__ void ecoord(int e, int& r, int& c, bool& dg) {
    int rr = 0;
    #pragma unroll
    for (int k = 1; k < 16; ++k) rr = (e >= tri(k)) ? k : rr;
    r = rr; c = e - tri(rr); dg = (c == rr);
}

// ---------------------------------------------------------------------------
__global__ __launch_bounds__(256) void hist_kernel(const int* __restrict__ segs,
                                                   int* __restrict__ cnt,
                                                   int* __restrict__ rank)
{
    int t = blockIdx.x * 256 + threadIdx.x;
    if (t < N_PTS) rank[t] = atomicAdd(&cnt[segs[t]], 1);
}

__global__ __launch_bounds__(256) void scan_blocks(const int* __restrict__ cnt,
                                                   int* __restrict__ off,
                                                   int* __restrict__ bsum)
{
    __shared__ int sh[256];
    const int t = threadIdx.x;
    const int i = blockIdx.x * 256 + t;
    int v = (i < NSEG) ? cnt[i] : 0;
    sh[t] = v;
    __syncthreads();
    #pragma unroll
    for (int d = 1; d < 256; d <<= 1) {
        int add = (t >= d) ? sh[t - d] : 0;
        __syncthreads();
        sh[t] += add;
        __syncthreads();
    }
    if (i < NSEG) off[i] = sh[t] - v;
    if (t == 255) bsum[blockIdx.x] = sh[t];
}

__global__ __launch_bounds__(512) void scan_top(int* __restrict__ bsum)
{
    __shared__ int sh[512];
    const int t = threadIdx.x;
    int v = (t < NB) ? bsum[t] : 0;
    sh[t] = v;
    __syncthreads();
    #pragma unroll
    for (int d = 1; d < 512; d <<= 1) {
        int add = (t >= d) ? sh[t - d] : 0;
        __syncthreads();
        sh[t] += add;
        __syncthreads();
    }
    if (t < NB) bsum[t] = sh[t] - v;
}

__global__ __launch_bounds__(256) void scan_add(int* __restrict__ off,
                                                const int* __restrict__ bsum)
{
    int i = blockIdx.x * 256 + threadIdx.x;
    if (i < NSEG) off[i] += bsum[blockIdx.x];
}

__global__ __launch_bounds__(256) void scatter_kernel(const int* __restrict__ segs,
                                                      const int* __restrict__ off,
                                                      const int* __restrict__ rank,
                                                      int* __restrict__ sorted)
{
    int t = blockIdx.x * 256 + threadIdx.x;
    if (t < N_PTS) sorted[off[segs[t]] + rank[t]] = t;
}

// ---------------------------------------------------------------------------
// main: one wave per SEGW consecutive segments.
// ---------------------------------------------------------------------------
__global__ __launch_bounds__(256, 2)
void main_kernel(const float* __restrict__ data,
                 const int*   __restrict__ segs,
                 const int*   __restrict__ sorted,
                 const int*   __restrict__ off,
                 const int*   __restrict__ cnt,
                 const float* __restrict__ W,
                 const float* __restrict__ bias,
                 float* __restrict__ Fred,
                 float* __restrict__ tred)
{
    // per wave: 16 points x (16 rows x stride-24 bf16) = 12288 B
    __shared__ __align__(16) unsigned short lds[4 * 6144];
    const int l = threadIdx.x & 63;
    const int w = threadIdx.x >> 6;
    unsigned short* Lw = &lds[w * 6144];
    const int c = l & 15;          // col-in-tile / D-col / A-row
    const int q = l >> 4;          // quad

    // zero L image once: pad cols (16..23) and strict-upper stay zero forever
    #pragma unroll
    for (int u = 0; u < 48; ++u) ((unsigned*)Lw)[u * 64 + l] = 0u;
    wave_lds_sync();

    // ---- register-cache W fragments (B-operand layout) + bias ----
    bf16x8 wf[10][2];
    float  bT[10];
    #pragma unroll
    for (int T = 0; T < 10; ++T) {
        #pragma unroll
        for (int ks = 0; ks < 2; ++ks) {
            bf16x8 f;
            #pragma unroll
            for (int j = 0; j < 8; ++j) {
                int k = 32 * ks + 8 * q + j;
                int n = 16 * T + c;
                f[j] = (n < NET_OUT) ? f2bf(W[k * NET_OUT + n]) : (short)0;
            }
            wf[T][ks] = f;
        }
        int n = 16 * T + c;
        bT[T] = (n < NET_OUT) ? bias[n] : 0.0f;
    }

    // ---- per-lane entry coords for T=1..9 (e = 16*(T-1)+c) ----
    int  rcoff[9];     // re*24 + ce (ushort units)
    bool dgm[9];
    #pragma unroll
    for (int T = 1; T <= 9; ++T) {
        int e = 16 * (T - 1) + c;
        int re, ce; bool dg;
        ecoord(e, re, ce, dg);
        rcoff[T - 1] = re * 24 + ce;
        dgm[T - 1]   = dg;
    }
    const bool v9 = (c < 8);       // T=9 valid only for c<8 (e<136)

    int trim[4], mrow[4];
    #pragma unroll
    for (int r = 0; r < 4; ++r) { mrow[r] = 4 * q + r; trim[r] = tri(4 * q + r); }

    const int wave_id = blockIdx.x * 4 + w;
    const int ws0 = wave_id * SEGW;
    if (ws0 >= NSEG) return;
    const int ws1 = min(ws0 + SEGW, NSEG);
    int g = off[ws0];
    const int gend = off[ws1 - 1] + cnt[ws1 - 1];

    f32x4 facc = {0.f, 0.f, 0.f, 0.f};
    float tcarry = 0.f;
    int a_start = 0;

    while (g < gend) {
        const int nv = min(16, gend - g);
        const int idx  = g + min(c, nv - 1);
        const int p    = sorted[idx];
        const int pn   = sorted[min(idx + 1, N_PTS - 1)];
        const int ssp  = segs[p];
        const int sspn = segs[pn];
        const bool flag = (idx == N_PTS - 1) || (sspn != ssp);
        const unsigned long long bm = __ballot(l < 16 && c < nv && flag);

        // ---- net GEMM: A-frags from gathered data rows ----
        bf16x8 af[2];
        #pragma unroll
        for (int ks = 0; ks < 2; ++ks) {
            const float4* dp = (const float4*)(data + (size_t)p * DIM + 32 * ks + 8 * q);
            float4 x0 = dp[0], x1 = dp[1];
            bf16x8 f;
            f[0] = f2bf(x0.x); f[1] = f2bf(x0.y); f[2] = f2bf(x0.z); f[3] = f2bf(x0.w);
            f[4] = f2bf(x1.x); f[5] = f2bf(x1.y); f[6] = f2bf(x1.z); f[7] = f2bf(x1.w);
            af[ks] = f;
        }
        f32x4 acc[10];
        #pragma unroll
        for (int T = 0; T < 10; ++T) {
            f32x4 z = {0.f, 0.f, 0.f, 0.f};
            z = __builtin_amdgcn_mfma_f32_16x16x32_bf16(af[0], wf[T][0], z, 0, 0, 0);
            acc[T] = __builtin_amdgcn_mfma_f32_16x16x32_bf16(af[1], wf[T][1], z, 0, 0, 0);
        }

        // ---- t prefix along point index m (rows of D tile 0) ----
        float s0 = acc[0][0] + bT[0];
        float s1 = s0 + acc[0][1] + bT[0];
        float s2 = s1 + acc[0][2] + bT[0];
        float s3 = s2 + acc[0][3] + bT[0];
        float u  = s3;
        float v16 = __shfl_up(u, 16, 64);
        float v32 = __shfl_up(u, 32, 64);
        float v48 = __shfl_up(u, 48, 64);
        float excl = (q >= 1 ? v16 : 0.f) + (q >= 2 ? v32 : 0.f) + (q >= 3 ? v48 : 0.f);
        float P0 = excl + s0, P1 = excl + s1, P2 = excl + s2, P3 = excl + s3;

        // ---- activations -> L image in LDS ----
        wave_lds_sync();                       // WAR vs previous tile's F reads
        #pragma unroll
        for (int T = 1; T <= 9; ++T) {
            #pragma unroll
            for (int r = 0; r < 4; ++r) {
                float v = fast_tanh(acc[T][r] + bT[T]);
                if (dgm[T - 1]) v = fast_softplus(v);
                if (T < 9 || v9)
                    Lw[mrow[r] * 384 + rcoff[T - 1]] = (unsigned short)f2bf(v);
            }
        }
        wave_lds_sync();                       // RAW: writes visible to F reads

        // ---- per-point F MFMA + segment accumulate / flush ----
        for (int i = 0; i < nv; ++i) {
            bf16x8 lf = {0, 0, 0, 0, 0, 0, 0, 0};
            if (q < 2)
                lf = *(const bf16x8*)(Lw + i * 384 + c * 24 + q * 8);
            facc = __builtin_amdgcn_mfma_f32_16x16x32_bf16(lf, lf, facc, 0, 0, 0);

            if ((bm >> i) & 1) {
                const int sid = __shfl(ssp, i, 64);
                // t flush: inclusive P at i minus exclusive at a_start
                int rs = i & 3;
                float vi = (rs == 0) ? P0 : (rs == 1) ? P1 : (rs == 2) ? P2 : P3;
                float Pi = __shfl(vi, ((i >> 2) << 4) | c, 64);
                float Pe = 0.f;
                if (a_start > 0) {
                    int aa = a_start - 1, ra = aa & 3;
                    float va = (ra == 0) ? P0 : (ra == 1) ? P1 : (ra == 2) ? P2 : P3;
                    Pe = __shfl(va, ((aa >> 2) << 4) | c, 64);
                }
                float ts = Pi - Pe + tcarry;
                if (l < 16) tred[(size_t)sid * INNER + c] = ts;
                tcarry = 0.f;
                #pragma unroll
                for (int r = 0; r < 4; ++r)
                    if (c <= mrow[r])
                        Fred[(size_t)sid * NTRI + trim[r] + c] = facc[r];
                facc = (f32x4){0.f, 0.f, 0.f, 0.f};
                a_start = i + 1;
            }
        }
        // carry open segment's t partial into next tile
        if (a_start < nv) {
            int ii = nv - 1, rs = ii & 3;
            float vi = (rs == 0) ? P0 : (rs == 1) ? P1 : (rs == 2) ? P2 : P3;
            float Pi = __shfl(vi, ((ii >> 2) << 4) | c, 64);
            float Pe = 0.f;
            if (a_start > 0) {
                int aa = a_start - 1, ra = aa & 3;
                float va = (ra == 0) ? P0 : (ra == 1) ? P1 : (ra == 2) ? P2 : P3;
                Pe = __shfl(va, ((aa >> 2) << 4) | c, 64);
            }
            tcarry += Pi - Pe;
        }
        a_start = 0;
        g += nv;
    }
}

// ---------------------------------------------------------------------------
// seg: per-thread packed Cholesky solve + GEMV (verified; + empty-seg guard)
// ---------------------------------------------------------------------------
__global__ __launch_bounds__(256, 2)
void seg_kernel(const float* __restrict__ Fred,
                const float* __restrict__ tred,
                const int*   __restrict__ cnt,
                const float* __restrict__ projW,
                float* __restrict__ out)
{
    const int s = blockIdx.x * 256 + threadIdx.x;
    if (s >= NSEG) return;
    float* orow = out + (size_t)s * OUTD;

    if (cnt[s] == 0) {   // empty segment: F=I, t=0 -> out=0 (Fred row is poison)
        float4 zz = {0.f, 0.f, 0.f, 0.f};
        #pragma unroll
        for (int oc = 0; oc < OUTD; oc += 4) *(float4*)(orow + oc) = zz;
        return;
    }

    float a[NTRI];
    const float4* f4 = (const float4*)(Fred + (size_t)s * NTRI);
    #pragma unroll
    for (int qq = 0; qq < NTRI / 4; ++qq) {
        float4 v = f4[qq];
        a[4 * qq + 0] = v.x; a[4 * qq + 1] = v.y;
        a[4 * qq + 2] = v.z; a[4 * qq + 3] = v.w;
    }
    #pragma unroll
    for (int ii = 0; ii < INNER; ++ii) a[tri(ii) + ii] += 1.0f;

    #pragma unroll
    for (int j = 0; j < INNER; ++j) {
        float d = a[tri(j) + j];
        #pragma unroll
        for (int k = 0; k < j; ++k)
            d = fmaf(-a[tri(j) + k], a[tri(j) + k], d);
        d = sqrtf(d);
        a[tri(j) + j] = d;
        float dinv = __fdividef(1.0f, d);
        #pragma unroll
        for (int ii = j + 1; ii < INNER; ++ii) {
            float v = a[tri(ii) + j];
            #pragma unroll
            for (int k = 0; k < j; ++k)
                v = fmaf(-a[tri(ii) + k], a[tri(j) + k], v);
            a[tri(ii) + j] = v * dinv;
        }
    }
    float z[INNER];
    #pragma unroll
    for (int ii = 0; ii < INNER; ++ii) {
        float v = 1.0f;
        #pragma unroll
        for (int k = 0; k < ii; ++k)
            v = fmaf(-a[tri(ii) + k], z[k], v);
        z[ii] = __fdividef(v, a[tri(ii) + ii]);
    }
    float x[INNER];
    #pragma unroll
    for (int ii = INNER - 1; ii >= 0; --ii) {
        float v = z[ii];
        #pragma unroll
        for (int k = ii + 1; k < INNER; ++k)
            v = fmaf(-a[tri(k) + ii], x[k], v);
        x[ii] = __fdividef(v, a[tri(ii) + ii]);
    }
    float theta[INNER];
    const float4* t4 = (const float4*)(tred + (size_t)s * INNER);
    #pragma unroll
    for (int qq = 0; qq < 4; ++qq) {
        float4 v = t4[qq];
        theta[4 * qq + 0] = v.x * x[4 * qq + 0];
        theta[4 * qq + 1] = v.y * x[4 * qq + 1];
        theta[4 * qq + 2] = v.z * x[4 * qq + 2];
        theta[4 * qq + 3] = v.w * x[4 * qq + 3];
    }
    for (int oc = 0; oc < OUTD; oc += 8) {
        float acc[8] = {0, 0, 0, 0, 0, 0, 0, 0};
        #pragma unroll
        for (int j = 0; j < INNER; ++j) {
            float th = theta[j];
            #pragma unroll
            for (int uu = 0; uu < 8; ++uu)
                acc[uu] = fmaf(th, projW[j * OUTD + oc + uu], acc[uu]);
        }
        float4 v0 = {acc[0], acc[1], acc[2], acc[3]};
        float4 v1 = {acc[4], acc[5], acc[6], acc[7]};
        ((float4*)(orow + oc))[0] = v0;
        ((float4*)(orow + oc))[1] = v1;
    }
}

extern "C" void kernel_launch(void* const* d_in, const int* in_sizes, int n_in,
                              void* d_out, int out_size, void* d_ws, size_t ws_size,
                              hipStream_t stream)
{
    const float* data  = (const float*)d_in[0];
    const int*   segs  = (const int*)d_in[1];
    const float* W     = (const float*)d_in[3];
    const float* bias  = (const float*)d_in[4];
    const float* projW = (const float*)d_in[5];

    int* cnt     = (int*)d_ws;                        // NSEG
    int* off     = cnt + NSEG;                        // NSEG
    int* bsum    = off + NSEG;                        // 512
    int* rank    = bsum + 512;                        // N_PTS
    int* sorted  = rank + N_PTS;                      // N_PTS
    float* Fred  = (float*)(sorted + N_PTS);          // NSEG*NTRI
    float* tred  = Fred + (size_t)NSEG * NTRI;        // NSEG*INNER

    hipMemsetAsync(cnt, 0, NSEG * sizeof(int), stream);

    hist_kernel   <<<(N_PTS + 255) / 256, 256, 0, stream>>>(segs, cnt, rank);
    scan_blocks   <<<NB, 256, 0, stream>>>(cnt, off, bsum);
    scan_top      <<<1, 512, 0, stream>>>(bsum);
    scan_add      <<<NB, 256, 0, stream>>>(off, bsum);
    scatter_kernel<<<(N_PTS + 255) / 256, 256, 0, stream>>>(segs, off, rank, sorted);
    main_kernel   <<<MAINB, 256, 0, stream>>>(data, segs, sorted, off, cnt, W, bias, Fred, tred);
    seg_kernel    <<<NB, 256, 0, stream>>>(Fred, tred, cnt, projW, (float*)d_out);
}